// Round 1
// baseline (103.278 us; speedup 1.0000x reference)
//
#include <hip/hip_runtime.h>
#include <math.h>

// IC loss: soft-rank (pairwise sigmoid row-sum) on predictions and targets,
// then negative Pearson correlation of the ranks.
//
// Stage A: rank_partial — 2 arrays x (N/256) i-tiles x JS j-slices blocks.
//   Each thread owns one i; j-slice staged in LDS (uniform-index broadcast
//   reads). sigmoid(xi - xj) = 1/(1 + exp(xj - xi)) -> v_exp_f32 + v_rcp_f32.
//   Partial row-sums combined with atomicAdd into d_ws ranks[2][N].
// Stage B: corr_kernel — single block, f64 moments, writes -ic.
// The "+1.0" in soft_rank is a constant shift; centering removes it -> skipped.

#define JS 8          // j-slices per array
#define BLK 256       // threads per block (one i per thread)

__global__ void rank_partial(const float* __restrict__ pred,
                             const float* __restrict__ targ,
                             float* __restrict__ ranks,   // [2][N] in ws
                             int N) {
    extern __shared__ float lds[];
    const int iTiles = (N + BLK - 1) / BLK;
    int bid    = blockIdx.x;
    int jSlice = bid % JS;
    int tmp    = bid / JS;
    int iTile  = tmp % iTiles;
    int arr    = tmp / iTiles;
    const float* __restrict__ x = (arr == 0) ? pred : targ;

    const int jlen = (N + JS - 1) / JS;
    const int j0   = jSlice * jlen;
    const int jend = min(N, j0 + jlen);
    const int cnt  = jend - j0;

    for (int j = threadIdx.x; j < cnt; j += BLK)
        lds[j] = x[j0 + j];
    __syncthreads();

    const int i = iTile * BLK + threadIdx.x;
    const float xi = (i < N) ? x[i] : 0.0f;

    float a0 = 0.f, a1 = 0.f, a2 = 0.f, a3 = 0.f;
    int j = 0;
    for (; j + 4 <= cnt; j += 4) {
        // uniform j across the wave -> LDS broadcast, no bank conflicts
        float4 v = *reinterpret_cast<const float4*>(&lds[j]);
        a0 += __builtin_amdgcn_rcpf(1.0f + __expf(v.x - xi));
        a1 += __builtin_amdgcn_rcpf(1.0f + __expf(v.y - xi));
        a2 += __builtin_amdgcn_rcpf(1.0f + __expf(v.z - xi));
        a3 += __builtin_amdgcn_rcpf(1.0f + __expf(v.w - xi));
    }
    for (; j < cnt; ++j)
        a0 += __builtin_amdgcn_rcpf(1.0f + __expf(lds[j] - xi));

    if (i < N)
        atomicAdd(&ranks[arr * N + i], (a0 + a1) + (a2 + a3));
}

__global__ void corr_kernel(const float* __restrict__ ranks,
                            float* __restrict__ out, int N) {
    const float* __restrict__ p = ranks;
    const float* __restrict__ t = ranks + N;

    double sp = 0, st = 0, spp = 0, stt = 0, spt = 0;
    for (int i = threadIdx.x; i < N; i += blockDim.x) {
        double a = p[i], b = t[i];
        sp  += a;     st  += b;
        spp += a * a; stt += b * b;
        spt += a * b;
    }
    // wave (64-lane) butterfly reduce
    for (int off = 32; off > 0; off >>= 1) {
        sp  += __shfl_down(sp,  off);
        st  += __shfl_down(st,  off);
        spp += __shfl_down(spp, off);
        stt += __shfl_down(stt, off);
        spt += __shfl_down(spt, off);
    }
    __shared__ double red[4][5];
    const int lane = threadIdx.x & 63;
    const int wave = threadIdx.x >> 6;
    if (lane == 0) {
        red[wave][0] = sp;  red[wave][1] = st;  red[wave][2] = spp;
        red[wave][3] = stt; red[wave][4] = spt;
    }
    __syncthreads();
    if (threadIdx.x == 0) {
        double Sp = 0, St = 0, Spp = 0, Stt = 0, Spt = 0;
        const int nw = blockDim.x >> 6;
        for (int w = 0; w < nw; ++w) {
            Sp += red[w][0]; St += red[w][1]; Spp += red[w][2];
            Stt += red[w][3]; Spt += red[w][4];
        }
        const double dn = (double)N;
        double num = Spt - Sp * St / dn;
        double vp  = Spp - Sp * Sp / dn;
        double vt  = Stt - St * St / dn;
        double ic  = num / (sqrt(vp * vt) + 1e-8);
        out[0] = (float)(-ic);
    }
}

extern "C" void kernel_launch(void* const* d_in, const int* in_sizes, int n_in,
                              void* d_out, int out_size, void* d_ws, size_t ws_size,
                              hipStream_t stream) {
    const float* pred = (const float*)d_in[0];
    const float* targ = (const float*)d_in[1];
    const int N = in_sizes[0];

    float* ranks = (float*)d_ws;                       // [2][N]
    hipMemsetAsync(d_ws, 0, (size_t)2 * N * sizeof(float), stream);

    const int iTiles = (N + BLK - 1) / BLK;
    const int blocks = 2 * iTiles * JS;
    const int jlen   = (N + JS - 1) / JS;
    rank_partial<<<blocks, BLK, jlen * sizeof(float), stream>>>(pred, targ, ranks, N);
    corr_kernel<<<1, 256, 0, stream>>>(ranks, (float*)d_out, N);
}